// Round 1
// baseline (900.317 us; speedup 1.0000x reference)
//
#include <hip/hip_runtime.h>
#include <math.h>

#define NN 50000
#define NE 800000
#define D 128
#define DE 16
#define NL 3
#define LN_EPS 1e-5f

// ---------------- preprocessing ----------------

__global__ void k_count(const int* __restrict__ col, int* __restrict__ cnt) {
  int e = blockIdx.x * blockDim.x + threadIdx.x;
  if (e < NE) atomicAdd(&cnt[col[e]], 1);
}

__global__ __launch_bounds__(1024) void k_scan(const int* __restrict__ cnt,
                                               int* __restrict__ col_ptr,
                                               int* __restrict__ cursor,
                                               float* __restrict__ dis) {
  __shared__ int buf[1024];
  __shared__ int carry;
  int t = threadIdx.x;
  if (t == 0) carry = 0;
  __syncthreads();
  for (int base = 0; base < NN; base += 1024) {
    int i = base + t;
    int v = (i < NN) ? cnt[i] : 0;
    buf[t] = v;
    __syncthreads();
    int acc = v;
    for (int off = 1; off < 1024; off <<= 1) {
      int add = (t >= off) ? buf[t - off] : 0;
      __syncthreads();
      acc += add;
      buf[t] = acc;
      __syncthreads();
    }
    int excl = acc - v;
    int base_carry = carry;
    if (i < NN) {
      int cp = base_carry + excl;
      col_ptr[i] = cp;
      cursor[i] = cp;
      dis[i] = (v > 0) ? rsqrtf((float)v) : 0.0f;
    }
    __syncthreads();
    if (t == 1023) carry = base_carry + buf[1023];
    __syncthreads();
  }
  if (t == 0) col_ptr[NN] = carry;
}

__global__ void k_fill(const int* __restrict__ row, const int* __restrict__ col,
                       int* __restrict__ cursor, int* __restrict__ csr_row,
                       int* __restrict__ csr_eid) {
  int e = blockIdx.x * blockDim.x + threadIdx.x;
  if (e < NE) {
    int c = col[e];
    int p = atomicAdd(&cursor[c], 1);
    csr_row[p] = row[e];
    csr_eid[p] = e;
  }
}

// ---------------- GEMM: C[M x 128] = A[M x 128] @ W[128 x 128] ----------------
// block: 256 threads, 64-row tile; thread = 8 rows x 4 cols.

__global__ __launch_bounds__(256, 4) void k_gemm(const float* __restrict__ A,
                                                 const float* __restrict__ W,
                                                 float* __restrict__ C) {
  __shared__ float As[64 * 128];
  int t = threadIdx.x;
  int m0 = blockIdx.x * 64;
  #pragma unroll
  for (int i = 0; i < 8; ++i) {
    int idx = (i * 256 + t) * 4;
    int r = m0 + (idx >> 7);
    float4 v = make_float4(0.f, 0.f, 0.f, 0.f);
    if (r < NN) v = *(const float4*)(A + (size_t)r * D + (idx & 127));
    *(float4*)(As + idx) = v;
  }
  __syncthreads();
  int tx = t & 31, ty = t >> 5;
  int c0 = tx * 4;
  float4 acc[8];
  #pragma unroll
  for (int r = 0; r < 8; ++r) acc[r] = make_float4(0.f, 0.f, 0.f, 0.f);
  const float* arow = As + (ty * 8) * D;
  #pragma unroll 8
  for (int k = 0; k < D; ++k) {
    float4 b = *(const float4*)(W + k * D + c0);
    #pragma unroll
    for (int r = 0; r < 8; ++r) {
      float a = arow[r * D + k];
      acc[r].x = fmaf(a, b.x, acc[r].x);
      acc[r].y = fmaf(a, b.y, acc[r].y);
      acc[r].z = fmaf(a, b.z, acc[r].z);
      acc[r].w = fmaf(a, b.w, acc[r].w);
    }
  }
  #pragma unroll
  for (int r = 0; r < 8; ++r) {
    int m = m0 + ty * 8 + r;
    if (m < NN) *(float4*)(C + (size_t)m * D + c0) = acc[r];
  }
}

// ---------------- GEMM2 + epilogue (bias terms, LayerNorm, relu) ----------------

__global__ __launch_bounds__(256, 4) void k_gemm_ln(
    const float* __restrict__ A,      // acc_e [N x 128]
    const float* __restrict__ W,      // edge_w2[l] [128 x 128]
    const float* __restrict__ accH,   // acc_h [N x 128]
    const int* __restrict__ cnt,      // in-degree
    const float* __restrict__ b2, const float* __restrict__ bias,
    const float* __restrict__ lnw, const float* __restrict__ lnb,
    float* __restrict__ Out) {
  __shared__ float As[64 * 128];
  int t = threadIdx.x;
  int m0 = blockIdx.x * 64;
  #pragma unroll
  for (int i = 0; i < 8; ++i) {
    int idx = (i * 256 + t) * 4;
    int r = m0 + (idx >> 7);
    float4 v = make_float4(0.f, 0.f, 0.f, 0.f);
    if (r < NN) v = *(const float4*)(A + (size_t)r * D + (idx & 127));
    *(float4*)(As + idx) = v;
  }
  __syncthreads();
  int tx = t & 31, ty = t >> 5;
  int c0 = tx * 4;
  float4 acc[8];
  #pragma unroll
  for (int r = 0; r < 8; ++r) acc[r] = make_float4(0.f, 0.f, 0.f, 0.f);
  const float* arow = As + (ty * 8) * D;
  #pragma unroll 8
  for (int k = 0; k < D; ++k) {
    float4 b = *(const float4*)(W + k * D + c0);
    #pragma unroll
    for (int r = 0; r < 8; ++r) {
      float a = arow[r * D + k];
      acc[r].x = fmaf(a, b.x, acc[r].x);
      acc[r].y = fmaf(a, b.y, acc[r].y);
      acc[r].z = fmaf(a, b.z, acc[r].z);
      acc[r].w = fmaf(a, b.w, acc[r].w);
    }
  }
  float4 b2v = *(const float4*)(b2 + c0);
  float4 biasv = *(const float4*)(bias + c0);
  float4 lnwv = *(const float4*)(lnw + c0);
  float4 lnbv = *(const float4*)(lnb + c0);
  #pragma unroll
  for (int r = 0; r < 8; ++r) {
    int m = m0 + ty * 8 + r;
    float4 v = acc[r];
    float4 ah = make_float4(0.f, 0.f, 0.f, 0.f);
    float degf = 0.f;
    if (m < NN) {
      ah = *(const float4*)(accH + (size_t)m * D + c0);
      degf = (float)cnt[m];
    }
    v.x += ah.x + degf * b2v.x + biasv.x;
    v.y += ah.y + degf * b2v.y + biasv.y;
    v.z += ah.z + degf * b2v.z + biasv.z;
    v.w += ah.w + degf * b2v.w + biasv.w;
    float s = v.x + v.y + v.z + v.w;
    float sq = v.x * v.x + v.y * v.y + v.z * v.z + v.w * v.w;
    #pragma unroll
    for (int off = 16; off >= 1; off >>= 1) {
      s += __shfl_xor(s, off, 32);
      sq += __shfl_xor(sq, off, 32);
    }
    float mu = s * (1.0f / D);
    float var = sq * (1.0f / D) - mu * mu;
    float rs = rsqrtf(var + LN_EPS);
    v.x = fmaxf((v.x - mu) * rs * lnwv.x + lnbv.x, 0.f);
    v.y = fmaxf((v.y - mu) * rs * lnwv.y + lnbv.y, 0.f);
    v.z = fmaxf((v.z - mu) * rs * lnwv.z + lnbv.z, 0.f);
    v.w = fmaxf((v.w - mu) * rs * lnwv.w + lnbv.w, 0.f);
    if (m < NN) *(float4*)(Out + (size_t)m * D + c0) = v;
  }
}

// ---------------- aggregation: wave per node, CSR gather ----------------
// acc_h[n] = sum_e w_e * hx[row_e];  acc_e[n] = sum_e relu(edge_attr[e] @ W1 + b1)

__global__ __launch_bounds__(256, 4) void k_aggregate(
    const float* __restrict__ hx, const float* __restrict__ edge_attr,
    const float* __restrict__ W1, const float* __restrict__ b1,
    const int* __restrict__ col_ptr, const int* __restrict__ csr_row,
    const int* __restrict__ csr_eid, const float* __restrict__ dis,
    float* __restrict__ acc_h, float* __restrict__ acc_e) {
  __shared__ float w1s[DE * D];
  __shared__ float b1s[D];
  int t = threadIdx.x;
  for (int i = t; i < DE * D; i += 256) w1s[i] = W1[i];
  if (t < D) b1s[t] = b1[t];
  __syncthreads();
  int lane = t & 63;
  int wid = __builtin_amdgcn_readfirstlane(t >> 6);
  int n = blockIdx.x * 4 + wid;
  if (n >= NN) return;
  float2 w1r[DE];
  #pragma unroll
  for (int k = 0; k < DE; ++k) w1r[k] = *(const float2*)&w1s[k * D + lane * 2];
  float2 b1v = *(const float2*)&b1s[lane * 2];
  int p0 = col_ptr[n], p1 = col_ptr[n + 1];
  float dn = dis[n];
  float2 aH = make_float2(0.f, 0.f);
  float2 aE = make_float2(0.f, 0.f);
  for (int p = p0; p < p1; ++p) {
    int r = csr_row[p];
    int eid = csr_eid[p];
    float we = dn * dis[r];
    float2 hv = *(const float2*)(hx + (size_t)r * D + lane * 2);
    aH.x = fmaf(we, hv.x, aH.x);
    aH.y = fmaf(we, hv.y, aH.y);
    const float4* ea = (const float4*)(edge_attr + (size_t)eid * DE);
    float4 a0 = ea[0], a1 = ea[1], a2 = ea[2], a3 = ea[3];
    float av[16];
    av[0] = a0.x; av[1] = a0.y; av[2] = a0.z; av[3] = a0.w;
    av[4] = a1.x; av[5] = a1.y; av[6] = a1.z; av[7] = a1.w;
    av[8] = a2.x; av[9] = a2.y; av[10] = a2.z; av[11] = a2.w;
    av[12] = a3.x; av[13] = a3.y; av[14] = a3.z; av[15] = a3.w;
    float2 sE = b1v;
    #pragma unroll
    for (int k = 0; k < DE; ++k) {
      sE.x = fmaf(av[k], w1r[k].x, sE.x);
      sE.y = fmaf(av[k], w1r[k].y, sE.y);
    }
    aE.x += fmaxf(sE.x, 0.f);
    aE.y += fmaxf(sE.y, 0.f);
  }
  *(float2*)(acc_h + (size_t)n * D + lane * 2) = aH;
  *(float2*)(acc_e + (size_t)n * D + lane * 2) = aE;
}

// ---------------- launch ----------------

static inline size_t align256(size_t x) { return (x + 255) & ~(size_t)255; }

extern "C" void kernel_launch(void* const* d_in, const int* in_sizes, int n_in,
                              void* d_out, int out_size, void* d_ws, size_t ws_size,
                              hipStream_t stream) {
  const float* x         = (const float*)d_in[0];
  const float* edge_attr = (const float*)d_in[1];
  const float* lin_w     = (const float*)d_in[2];
  const float* edge_w1   = (const float*)d_in[3];
  const float* edge_b1   = (const float*)d_in[4];
  const float* edge_w2   = (const float*)d_in[5];
  const float* edge_b2   = (const float*)d_in[6];
  const float* bias      = (const float*)d_in[7];
  const float* ln_w      = (const float*)d_in[8];
  const float* ln_b      = (const float*)d_in[9];
  const int*   edge_idx  = (const int*)d_in[10];
  const int* row = edge_idx;
  const int* col = edge_idx + NE;
  float* out = (float*)d_out;

  char* w = (char*)d_ws;
  size_t off = 0;
  int* cnt     = (int*)(w + off); off = align256(off + sizeof(int) * NN);
  int* cursor  = (int*)(w + off); off = align256(off + sizeof(int) * NN);
  int* col_ptr = (int*)(w + off); off = align256(off + sizeof(int) * (NN + 1));
  float* dis   = (float*)(w + off); off = align256(off + sizeof(float) * NN);
  int* csr_row = (int*)(w + off); off = align256(off + sizeof(int) * NE);
  int* csr_eid = (int*)(w + off); off = align256(off + sizeof(int) * NE);
  float* hx    = (float*)(w + off); off = align256(off + sizeof(float) * (size_t)NN * D);
  float* acc_h = (float*)(w + off); off = align256(off + sizeof(float) * (size_t)NN * D);
  float* acc_e = (float*)(w + off); off = align256(off + sizeof(float) * (size_t)NN * D);
  float* h_buf = (float*)(w + off); off = align256(off + sizeof(float) * (size_t)NN * D);

  hipMemsetAsync(cnt, 0, sizeof(int) * NN, stream);

  k_count<<<(NE + 255) / 256, 256, 0, stream>>>(col, cnt);
  k_scan<<<1, 1024, 0, stream>>>(cnt, col_ptr, cursor, dis);
  k_fill<<<(NE + 255) / 256, 256, 0, stream>>>(row, col, cursor, csr_row, csr_eid);

  const int gemm_blocks = (NN + 63) / 64;
  for (int l = 0; l < NL; ++l) {
    const float* hin = (l == 0) ? x : h_buf;
    float* hout = (l == NL - 1) ? out : h_buf;
    k_gemm<<<gemm_blocks, 256, 0, stream>>>(hin, lin_w + (size_t)l * D * D, hx);
    k_aggregate<<<(NN + 3) / 4, 256, 0, stream>>>(
        hx, edge_attr, edge_w1 + (size_t)l * DE * D, edge_b1 + (size_t)l * D,
        col_ptr, csr_row, csr_eid, dis, acc_h, acc_e);
    k_gemm_ln<<<gemm_blocks, 256, 0, stream>>>(
        acc_e, edge_w2 + (size_t)l * D * D, acc_h, cnt,
        edge_b2 + (size_t)l * D, bias + (size_t)l * D,
        ln_w + (size_t)l * D, ln_b + (size_t)l * D, hout);
  }
}

// Round 2
// 671.750 us; speedup vs baseline: 1.3403x; 1.3403x over previous
//
#include <hip/hip_runtime.h>
#include <math.h>

#define NN 50000
#define NPAD 50048           // 782 * 64
#define NE 800000
#define D 128
#define DE 16
#define NL 3
#define LN_EPS 1e-5f
#define NB_SCAN 49           // ceil(50000/1024)

typedef __attribute__((ext_vector_type(8))) short short8;
typedef __attribute__((ext_vector_type(8))) unsigned short ushort8;
typedef __attribute__((ext_vector_type(4))) float floatx4;

__device__ __forceinline__ unsigned short f2bf(float f) {
  unsigned u = __float_as_uint(f);
  u = (u + 0x7fffu + ((u >> 16) & 1u)) >> 16;
  return (unsigned short)u;
}
__device__ __forceinline__ float bfl(unsigned v) { return __uint_as_float(v << 16); }
__device__ __forceinline__ float bfh(unsigned v) { return __uint_as_float(v & 0xffff0000u); }

// ---------------- preprocessing ----------------

__global__ void k_hist(const int* __restrict__ col, int* __restrict__ cnt) {
  int e = blockIdx.x * blockDim.x + threadIdx.x;
  if (e < NE) atomicAdd(&cnt[col[e]], 1);
}

__global__ __launch_bounds__(1024) void k_chunk_sum(const int* __restrict__ cnt,
                                                    int* __restrict__ chunk_sum) {
  int i = blockIdx.x * 1024 + threadIdx.x;
  int v = (i < NN) ? cnt[i] : 0;
  #pragma unroll
  for (int off = 32; off; off >>= 1) v += __shfl_down(v, off);
  __shared__ int ws_[16];
  int lane = threadIdx.x & 63, w = threadIdx.x >> 6;
  if (lane == 0) ws_[w] = v;
  __syncthreads();
  if (threadIdx.x < 16) {
    int s = ws_[threadIdx.x];
    #pragma unroll
    for (int off = 8; off; off >>= 1) s += __shfl_down(s, off);
    if (threadIdx.x == 0) chunk_sum[blockIdx.x] = s;
  }
}

__global__ __launch_bounds__(64) void k_chunk_scan(const int* __restrict__ chunk_sum,
                                                   int* __restrict__ chunk_off,
                                                   int* __restrict__ col_ptr) {
  int t = threadIdx.x;
  int v = (t < NB_SCAN) ? chunk_sum[t] : 0;
  int incl = v;
  #pragma unroll
  for (int off = 1; off < 64; off <<= 1) {
    int u = __shfl_up(incl, off);
    if (t >= off) incl += u;
  }
  if (t < NB_SCAN) chunk_off[t] = incl - v;
  if (t == 63) col_ptr[NN] = incl;   // total == NE
}

__global__ __launch_bounds__(1024) void k_scan_apply(const int* __restrict__ cnt,
                                                     const int* __restrict__ chunk_off,
                                                     int* __restrict__ col_ptr,
                                                     int* __restrict__ cursor,
                                                     float* __restrict__ dis) {
  __shared__ int buf[1024];
  int t = threadIdx.x;
  int i = blockIdx.x * 1024 + t;
  int v = (i < NN) ? cnt[i] : 0;
  buf[t] = v;
  __syncthreads();
  int acc = v;
  for (int off = 1; off < 1024; off <<= 1) {
    int add = (t >= off) ? buf[t - off] : 0;
    __syncthreads();
    acc += add;
    buf[t] = acc;
    __syncthreads();
  }
  if (i < NN) {
    int cp = chunk_off[blockIdx.x] + acc - v;
    col_ptr[i] = cp;
    cursor[i] = cp;
    dis[i] = (v > 0) ? rsqrtf((float)v) : 0.0f;
  }
}

__global__ void k_fill(const int* __restrict__ row, const int* __restrict__ col,
                       const float* __restrict__ dis, int* __restrict__ cursor,
                       int2* __restrict__ csr_rw, int* __restrict__ csr_eid) {
  int e = blockIdx.x * blockDim.x + threadIdx.x;
  if (e < NE) {
    int c = col[e], r = row[e];
    float w = dis[r] * dis[c];
    int p = atomicAdd(&cursor[c], 1);
    csr_rw[p] = make_int2(r, __float_as_int(w));
    csr_eid[p] = e;
  }
}

// convert+transpose weights: wt[(l*2+s)][n][k] = W_s[l][k][n] in bf16
__global__ void k_prep_w(const float* __restrict__ lin_w, const float* __restrict__ edge_w2,
                         unsigned short* __restrict__ wt) {
  int idx = blockIdx.x * blockDim.x + threadIdx.x;
  if (idx >= NL * 2 * D * D) return;
  int ls = idx / (D * D);
  int rem = idx - ls * (D * D);
  int n = rem >> 7, k = rem & 127;
  int l = ls >> 1, s = ls & 1;
  const float* W = (s == 0) ? (lin_w + (size_t)l * D * D) : (edge_w2 + (size_t)l * D * D);
  wt[idx] = f2bf(W[k * D + n]);
}

__global__ void k_cvt_x(const float* __restrict__ x, unsigned short* __restrict__ h) {
  int i = blockIdx.x * blockDim.x + threadIdx.x;
  if (i >= NN * D / 4) return;
  float4 v = ((const float4*)x)[i];
  ushort4 o;
  o.x = f2bf(v.x); o.y = f2bf(v.y); o.z = f2bf(v.z); o.w = f2bf(v.w);
  ((ushort4*)h)[i] = o;
}

// ---------------- gather + edge-MLP aggregation (wave per node) ----------------
// Abuf[n][0:128]   = agg_h  = sum_e w_e * h[row_e]           (bf16)
// Abuf[n][128:256] = acc_e  = sum_e relu(edge_attr[e]@W1+b1) (bf16)

__global__ __launch_bounds__(256, 4) void k_gather_mlp(
    const unsigned short* __restrict__ hIn, const float* __restrict__ edge_attr,
    const float* __restrict__ W1, const float* __restrict__ b1,
    const int* __restrict__ col_ptr, const int2* __restrict__ csr_rw,
    const int* __restrict__ csr_eid, unsigned int* __restrict__ Abuf) {
  __shared__ float w1s[DE * D];
  __shared__ float b1s[D];
  int t = threadIdx.x;
  for (int i = t; i < DE * D; i += 256) w1s[i] = W1[i];
  if (t < D) b1s[t] = b1[t];
  __syncthreads();
  int lane = t & 63;
  int n = blockIdx.x * 4 + (t >> 6);
  float2 w1r[DE];
  #pragma unroll
  for (int k = 0; k < DE; ++k) w1r[k] = *(const float2*)&w1s[k * D + lane * 2];
  float2 b1v = *(const float2*)&b1s[lane * 2];
  if (n >= NN) return;
  int p0 = col_ptr[n], p1 = col_ptr[n + 1];
  float aH0 = 0.f, aH1 = 0.f, aE0 = 0.f, aE1 = 0.f;

  auto doEdge = [&](int r, float wgt, int e) {
    unsigned hp = *(const unsigned*)(hIn + (((size_t)r) << 7) + (lane << 1));
    const float4* ea = (const float4*)(edge_attr + (((size_t)e) << 4));
    float q[16];
    *(float4*)&q[0] = ea[0];
    *(float4*)&q[4] = ea[1];
    float s0 = b1v.x, s1 = b1v.y;
    #pragma unroll
    for (int k = 0; k < 8; ++k) {
      s0 = fmaf(q[k], w1r[k].x, s0);
      s1 = fmaf(q[k], w1r[k].y, s1);
    }
    *(float4*)&q[8]  = ea[2];
    *(float4*)&q[12] = ea[3];
    #pragma unroll
    for (int k = 8; k < 16; ++k) {
      s0 = fmaf(q[k], w1r[k].x, s0);
      s1 = fmaf(q[k], w1r[k].y, s1);
    }
    aE0 += fmaxf(s0, 0.f);
    aE1 += fmaxf(s1, 0.f);
    aH0 = fmaf(wgt, bfl(hp), aH0);
    aH1 = fmaf(wgt, bfh(hp), aH1);
  };

  for (int base = p0; base < p1; base += 64) {
    int rem = p1 - base;
    if (rem > 64) rem = 64;
    int rX = 0, rW = 0, rEi = 0;
    if (lane < rem) {
      int2 qq = csr_rw[base + lane];
      rX = qq.x; rW = qq.y;
      rEi = csr_eid[base + lane];
    }
    int j = 0;
    for (; j + 4 <= rem; j += 4) {
      int   r0 = __shfl(rX, j + 0), r1 = __shfl(rX, j + 1), r2 = __shfl(rX, j + 2), r3 = __shfl(rX, j + 3);
      float w0 = __int_as_float(__shfl(rW, j + 0)), w1 = __int_as_float(__shfl(rW, j + 1));
      float w2 = __int_as_float(__shfl(rW, j + 2)), w3 = __int_as_float(__shfl(rW, j + 3));
      int   e0 = __shfl(rEi, j + 0), e1 = __shfl(rEi, j + 1), e2 = __shfl(rEi, j + 2), e3 = __shfl(rEi, j + 3);
      doEdge(r0, w0, e0);
      doEdge(r1, w1, e1);
      doEdge(r2, w2, e2);
      doEdge(r3, w3, e3);
    }
    for (; j < rem; ++j) {
      int   r0 = __shfl(rX, j);
      float w0 = __int_as_float(__shfl(rW, j));
      int   e0 = __shfl(rEi, j);
      doEdge(r0, w0, e0);
    }
  }
  unsigned* rowp = Abuf + (size_t)n * 128;
  rowp[lane]      = (unsigned)f2bf(aH0) | ((unsigned)f2bf(aH1) << 16);
  rowp[64 + lane] = (unsigned)f2bf(aE0) | ((unsigned)f2bf(aE1) << 16);
}

// ---------------- fused MFMA GEMM (K=256) + bias/deg + LayerNorm + relu ----------------
// out[m][n] = LN( sum_k Abuf[m][k] * Wcat[k][n] + deg[m]*b2[n] + bias[n] )
// Wcat = [lin_w ; edge_w2] pre-transposed to wt[slab][n][k] bf16.

template <bool LAST>
__global__ __launch_bounds__(256, 4) void k_fused(
    const unsigned short* __restrict__ Abuf,   // [NPAD][256] bf16
    const unsigned short* __restrict__ wtL,    // [2][128][128] bf16 (this layer)
    const int* __restrict__ cnt,
    const float* __restrict__ b2, const float* __restrict__ bias,
    const float* __restrict__ lnw, const float* __restrict__ lnb,
    unsigned short* __restrict__ hOut, float* __restrict__ fOut) {
  __shared__ unsigned short bt[128 * 128];   // XOR-swizzled 16B chunks
  int t = threadIdx.x;
  int w = t >> 6, lane = t & 63;
  int quad = lane >> 4, ln = lane & 15;
  int rowBase = blockIdx.x * 64 + w * 16;

  floatx4 acc[8];
  floatx4 zero = {0.f, 0.f, 0.f, 0.f};
  #pragma unroll
  for (int i = 0; i < 8; ++i) acc[i] = zero;

  float b2n[8], biasn[8], lnwn[8], lnbn[8];
  #pragma unroll
  for (int i = 0; i < 8; ++i) {
    int nc = i * 16 + ln;
    b2n[i] = b2[nc]; biasn[i] = bias[nc]; lnwn[i] = lnw[nc]; lnbn[i] = lnb[nc];
  }

  const unsigned short* Arow = Abuf + (size_t)(rowBase + ln) * 256;

  #pragma unroll
  for (int p = 0; p < 2; ++p) {
    if (p) __syncthreads();
    const unsigned short* src = wtL + p * (D * D);
    #pragma unroll
    for (int j = 0; j < 8; ++j) {
      int E = t * 8 + j * 2048;                  // element index: n*128 + k
      int nn_ = E >> 7, kblk = (E & 127) >> 3;
      int dst = nn_ * 128 + ((kblk ^ (nn_ & 15)) << 3);
      *(ushort8*)&bt[dst] = *(const ushort8*)&src[E];
    }
    __syncthreads();
    #pragma unroll
    for (int k0 = 0; k0 < 128; k0 += 32) {
      short8 a = *(const short8*)(const void*)(Arow + p * 128 + k0 + quad * 8);
      int cblk = (k0 >> 3) + quad;
      #pragma unroll
      for (int tt = 0; tt < 8; ++tt) {
        int src_off = (tt * 16 + ln) * 128 + ((cblk ^ ln) << 3);
        short8 b = *(const short8*)(const void*)&bt[src_off];
        acc[tt] = __builtin_amdgcn_mfma_f32_16x16x32_bf16(a, b, acc[tt], 0, 0, 0);
      }
    }
  }

  // epilogue: D[m=quad*4+r][n=tt*16+ln]
  float degf[4];
  #pragma unroll
  for (int r = 0; r < 4; ++r) {
    int m = rowBase + quad * 4 + r;
    degf[r] = (m < NN) ? (float)cnt[m] : 0.f;
  }
  float v[8][4];
  float s[4] = {0, 0, 0, 0}, sq[4] = {0, 0, 0, 0};
  #pragma unroll
  for (int tt = 0; tt < 8; ++tt) {
    #pragma unroll
    for (int r = 0; r < 4; ++r) {
      float x = acc[tt][r] + degf[r] * b2n[tt] + biasn[tt];
      v[tt][r] = x;
      s[r] += x;
      sq[r] += x * x;
    }
  }
  #pragma unroll
  for (int r = 0; r < 4; ++r) {
    #pragma unroll
    for (int m_ = 8; m_ >= 1; m_ >>= 1) {
      s[r] += __shfl_xor(s[r], m_);
      sq[r] += __shfl_xor(sq[r], m_);
    }
  }
  #pragma unroll
  for (int r = 0; r < 4; ++r) {
    int m = rowBase + quad * 4 + r;
    float mu = s[r] * (1.f / D);
    float var = sq[r] * (1.f / D) - mu * mu;
    float rs = rsqrtf(var + LN_EPS);
    if (m < NN) {
      #pragma unroll
      for (int tt = 0; tt < 8; ++tt) {
        float y = fmaxf((v[tt][r] - mu) * rs * lnwn[tt] + lnbn[tt], 0.f);
        int nc = tt * 16 + ln;
        if (LAST) fOut[(size_t)m * D + nc] = y;
        else      hOut[(size_t)m * D + nc] = f2bf(y);
      }
    }
  }
}

// ---------------- launch ----------------

static inline size_t align256(size_t x) { return (x + 255) & ~(size_t)255; }

extern "C" void kernel_launch(void* const* d_in, const int* in_sizes, int n_in,
                              void* d_out, int out_size, void* d_ws, size_t ws_size,
                              hipStream_t stream) {
  const float* x         = (const float*)d_in[0];
  const float* edge_attr = (const float*)d_in[1];
  const float* lin_w     = (const float*)d_in[2];
  const float* edge_w1   = (const float*)d_in[3];
  const float* edge_b1   = (const float*)d_in[4];
  const float* edge_w2   = (const float*)d_in[5];
  const float* edge_b2   = (const float*)d_in[6];
  const float* bias      = (const float*)d_in[7];
  const float* ln_w      = (const float*)d_in[8];
  const float* ln_b      = (const float*)d_in[9];
  const int*   edge_idx  = (const int*)d_in[10];
  const int* row = edge_idx;
  const int* col = edge_idx + NE;
  float* out = (float*)d_out;

  char* wsp = (char*)d_ws;
  size_t off = 0;
  int* cnt       = (int*)(wsp + off); off = align256(off + sizeof(int) * NN);
  int* cursor    = (int*)(wsp + off); off = align256(off + sizeof(int) * NN);
  int* col_ptr   = (int*)(wsp + off); off = align256(off + sizeof(int) * (NN + 1));
  float* dis     = (float*)(wsp + off); off = align256(off + sizeof(float) * NN);
  int* chunk_sum = (int*)(wsp + off); off = align256(off + sizeof(int) * 64);
  int* chunk_off = (int*)(wsp + off); off = align256(off + sizeof(int) * 64);
  int2* csr_rw   = (int2*)(wsp + off); off = align256(off + sizeof(int2) * NE);
  int* csr_eid   = (int*)(wsp + off); off = align256(off + sizeof(int) * NE);
  unsigned short* wt = (unsigned short*)(wsp + off); off = align256(off + sizeof(short) * NL * 2 * D * D);
  unsigned short* hA = (unsigned short*)(wsp + off); off = align256(off + sizeof(short) * (size_t)NPAD * D);
  unsigned short* hB = (unsigned short*)(wsp + off); off = align256(off + sizeof(short) * (size_t)NPAD * D);
  unsigned short* Abuf = (unsigned short*)(wsp + off); off = align256(off + sizeof(short) * (size_t)NPAD * 256);

  hipMemsetAsync(cnt, 0, sizeof(int) * NN, stream);

  k_hist<<<(NE + 255) / 256, 256, 0, stream>>>(col, cnt);
  k_chunk_sum<<<NB_SCAN, 1024, 0, stream>>>(cnt, chunk_sum);
  k_chunk_scan<<<1, 64, 0, stream>>>(chunk_sum, chunk_off, col_ptr);
  k_scan_apply<<<NB_SCAN, 1024, 0, stream>>>(cnt, chunk_off, col_ptr, cursor, dis);
  k_fill<<<(NE + 255) / 256, 256, 0, stream>>>(row, col, dis, cursor, csr_rw, csr_eid);
  k_prep_w<<<(NL * 2 * D * D + 255) / 256, 256, 0, stream>>>(lin_w, edge_w2, wt);
  k_cvt_x<<<(NN * D / 4 + 255) / 256, 256, 0, stream>>>(x, hA);

  const int fused_blocks = NPAD / 64;
  unsigned short* hcur = hA;
  unsigned short* hnxt = hB;
  for (int l = 0; l < NL; ++l) {
    k_gather_mlp<<<(NN + 3) / 4, 256, 0, stream>>>(
        hcur, edge_attr, edge_w1 + (size_t)l * DE * D, edge_b1 + (size_t)l * D,
        col_ptr, csr_rw, csr_eid, (unsigned int*)Abuf);
    const unsigned short* wtL = wt + (size_t)l * 2 * D * D;
    const float* b2L = edge_b2 + (size_t)l * D;
    const float* biasL = bias + (size_t)l * D;
    const float* lnwL = ln_w + (size_t)l * D;
    const float* lnbL = ln_b + (size_t)l * D;
    if (l == NL - 1) {
      k_fused<true><<<fused_blocks, 256, 0, stream>>>(Abuf, wtL, cnt, b2L, biasL, lnwL, lnbL,
                                                      (unsigned short*)nullptr, out);
    } else {
      k_fused<false><<<fused_blocks, 256, 0, stream>>>(Abuf, wtL, cnt, b2L, biasL, lnwL, lnbL,
                                                       hnxt, (float*)nullptr);
    }
    unsigned short* tmp = hcur; hcur = hnxt; hnxt = tmp;
  }
}

// Round 3
// 499.052 us; speedup vs baseline: 1.8041x; 1.3461x over previous
//
#include <hip/hip_runtime.h>
#include <math.h>

#define NN 50000
#define NPAD 50048           // 782 * 64
#define NE 800000
#define D 128
#define DE 16
#define NL 3
#define LN_EPS 1e-5f
#define NB_SCAN 49           // ceil(50000/1024)

typedef __attribute__((ext_vector_type(8))) short short8;
typedef __attribute__((ext_vector_type(8))) unsigned short ushort8;
typedef __attribute__((ext_vector_type(4))) float floatx4;

__device__ __forceinline__ unsigned short f2bf(float f) {
  unsigned u = __float_as_uint(f);
  u = (u + 0x7fffu + ((u >> 16) & 1u)) >> 16;
  return (unsigned short)u;
}
__device__ __forceinline__ float bfl(unsigned v) { return __uint_as_float(v << 16); }
__device__ __forceinline__ float bfh(unsigned v) { return __uint_as_float(v & 0xffff0000u); }

// ---------------- preprocessing ----------------

__global__ void k_hist(const int* __restrict__ col, int* __restrict__ cnt) {
  int e = blockIdx.x * blockDim.x + threadIdx.x;
  if (e < NE) atomicAdd(&cnt[col[e]], 1);
}

__global__ __launch_bounds__(1024) void k_chunk_sum(const int* __restrict__ cnt,
                                                    int* __restrict__ chunk_sum) {
  int i = blockIdx.x * 1024 + threadIdx.x;
  int v = (i < NN) ? cnt[i] : 0;
  #pragma unroll
  for (int off = 32; off; off >>= 1) v += __shfl_down(v, off);
  __shared__ int ws_[16];
  int lane = threadIdx.x & 63, w = threadIdx.x >> 6;
  if (lane == 0) ws_[w] = v;
  __syncthreads();
  if (threadIdx.x < 16) {
    int s = ws_[threadIdx.x];
    #pragma unroll
    for (int off = 8; off; off >>= 1) s += __shfl_down(s, off);
    if (threadIdx.x == 0) chunk_sum[blockIdx.x] = s;
  }
}

__global__ __launch_bounds__(64) void k_chunk_scan(const int* __restrict__ chunk_sum,
                                                   int* __restrict__ chunk_off,
                                                   int* __restrict__ col_ptr) {
  int t = threadIdx.x;
  int v = (t < NB_SCAN) ? chunk_sum[t] : 0;
  int incl = v;
  #pragma unroll
  for (int off = 1; off < 64; off <<= 1) {
    int u = __shfl_up(incl, off);
    if (t >= off) incl += u;
  }
  if (t < NB_SCAN) chunk_off[t] = incl - v;
  if (t == 63) col_ptr[NN] = incl;   // total == NE
}

__global__ __launch_bounds__(1024) void k_scan_apply(const int* __restrict__ cnt,
                                                     const int* __restrict__ chunk_off,
                                                     int* __restrict__ col_ptr,
                                                     int* __restrict__ cursor,
                                                     float* __restrict__ dis) {
  __shared__ int buf[1024];
  int t = threadIdx.x;
  int i = blockIdx.x * 1024 + t;
  int v = (i < NN) ? cnt[i] : 0;
  buf[t] = v;
  __syncthreads();
  int acc = v;
  for (int off = 1; off < 1024; off <<= 1) {
    int add = (t >= off) ? buf[t - off] : 0;
    __syncthreads();
    acc += add;
    buf[t] = acc;
    __syncthreads();
  }
  if (i < NN) {
    int cp = chunk_off[blockIdx.x] + acc - v;
    col_ptr[i] = cp;
    cursor[i] = cp;
    dis[i] = (v > 0) ? rsqrtf((float)v) : 0.0f;
  }
}

__global__ void k_fill(const int* __restrict__ row, const int* __restrict__ col,
                       const float* __restrict__ dis, int* __restrict__ cursor,
                       int2* __restrict__ csr_rw, int* __restrict__ csr_eid) {
  int e = blockIdx.x * blockDim.x + threadIdx.x;
  if (e < NE) {
    int c = col[e], r = row[e];
    float w = dis[r] * dis[c];
    int p = atomicAdd(&cursor[c], 1);
    csr_rw[p] = make_int2(r, __float_as_int(w));
    csr_eid[p] = e;
  }
}

// edge_attr permuted to CSR order, bf16: attr_bf[p][16]
__global__ void k_cvt_attr(const float* __restrict__ edge_attr, const int* __restrict__ csr_eid,
                           unsigned short* __restrict__ attr_bf) {
  int p = blockIdx.x * blockDim.x + threadIdx.x;
  if (p >= NE) return;
  int e = csr_eid[p];
  const float4* src = (const float4*)(edge_attr + ((size_t)e << 4));
  float4 f0 = src[0], f1 = src[1], f2 = src[2], f3 = src[3];
  ushort8 o0, o1;
  o0[0] = f2bf(f0.x); o0[1] = f2bf(f0.y); o0[2] = f2bf(f0.z); o0[3] = f2bf(f0.w);
  o0[4] = f2bf(f1.x); o0[5] = f2bf(f1.y); o0[6] = f2bf(f1.z); o0[7] = f2bf(f1.w);
  o1[0] = f2bf(f2.x); o1[1] = f2bf(f2.y); o1[2] = f2bf(f2.z); o1[3] = f2bf(f2.w);
  o1[4] = f2bf(f3.x); o1[5] = f2bf(f3.y); o1[6] = f2bf(f3.z); o1[7] = f2bf(f3.w);
  ushort8* dst = (ushort8*)(attr_bf + ((size_t)p << 4));
  dst[0] = o0;
  dst[1] = o1;
}

// convert+transpose weights: wt[(l*2+s)][n][k] = W_s[l][k][n] in bf16
__global__ void k_prep_w(const float* __restrict__ lin_w, const float* __restrict__ edge_w2,
                         unsigned short* __restrict__ wt) {
  int idx = blockIdx.x * blockDim.x + threadIdx.x;
  if (idx >= NL * 2 * D * D) return;
  int ls = idx / (D * D);
  int rem = idx - ls * (D * D);
  int n = rem >> 7, k = rem & 127;
  int l = ls >> 1, s = ls & 1;
  const float* W = (s == 0) ? (lin_w + (size_t)l * D * D) : (edge_w2 + (size_t)l * D * D);
  wt[idx] = f2bf(W[k * D + n]);
}

// W1^T fragments: w1t[l][n][k], k in [0,32): k<16 -> W1[k][n]; k==16 -> b1[n]; else 0
__global__ void k_prep_w1(const float* __restrict__ edge_w1, const float* __restrict__ edge_b1,
                          unsigned short* __restrict__ w1t) {
  int idx = blockIdx.x * blockDim.x + threadIdx.x;
  if (idx >= NL * D * 32) return;
  int l = idx / (D * 32);
  int rem = idx - l * (D * 32);
  int nf = rem >> 5, k = rem & 31;
  float v = 0.f;
  if (k < DE) v = edge_w1[(size_t)l * DE * D + k * D + nf];
  else if (k == DE) v = edge_b1[(size_t)l * D + nf];
  w1t[idx] = f2bf(v);
}

__global__ void k_cvt_x(const float* __restrict__ x, unsigned short* __restrict__ h) {
  int i = blockIdx.x * blockDim.x + threadIdx.x;
  if (i >= NN * D / 4) return;
  float4 v = ((const float4*)x)[i];
  ushort4 o;
  o.x = f2bf(v.x); o.y = f2bf(v.y); o.z = f2bf(v.z); o.w = f2bf(v.w);
  ((ushort4*)h)[i] = o;
}

// ---------------- aggregation: wave per node ----------------
// Abuf[n][0:128]   = agg_h = sum_e w_e * h[row_e]            (bf16, VALU gather)
// Abuf[n][128:256] = acc_e = sum_e relu(attr_e @ W1 + b1)    (bf16, MFMA per 16-edge group)

__global__ __launch_bounds__(256, 4) void k_agg(
    const unsigned short* __restrict__ hIn, const unsigned short* __restrict__ attr_bf,
    const unsigned short* __restrict__ w1tL,
    const int* __restrict__ col_ptr, const int2* __restrict__ csr_rw,
    unsigned short* __restrict__ Abuf) {
  int t = threadIdx.x;
  int lane = t & 63;
  int quad = lane >> 4, mrow = lane & 15;
  int n = blockIdx.x * 4 + (t >> 6);
  if (n >= NN) return;

  // B fragments for the 8 n-tiles of W1cat^T (constant per layer)
  short8 bfr[8];
  #pragma unroll
  for (int tt = 0; tt < 8; ++tt)
    bfr[tt] = *(const short8*)(const void*)(w1tL + (tt * 16 + mrow) * 32 + quad * 8);

  int p0 = col_ptr[n], p1 = col_ptr[n + 1];
  float aH0 = 0.f, aH1 = 0.f;
  float sE[8];
  #pragma unroll
  for (int tt = 0; tt < 8; ++tt) sE[tt] = 0.f;

  auto doGather = [&](int r, float wgt) {
    unsigned hp = *(const unsigned*)(hIn + (((size_t)r) << 7) + (lane << 1));
    aH0 = fmaf(wgt, bfl(hp), aH0);
    aH1 = fmaf(wgt, bfh(hp), aH1);
  };

  for (int base = p0; base < p1; base += 64) {
    int rem = p1 - base;
    if (rem > 64) rem = 64;
    int rX = 0, rW = 0;
    if (lane < rem) {
      int2 qq = csr_rw[base + lane];
      rX = qq.x; rW = qq.y;
    }
    // ---- h gather (feature-parallel, edges sequential) ----
    int j = 0;
    for (; j + 4 <= rem; j += 4) {
      int   r0 = __shfl(rX, j + 0), r1 = __shfl(rX, j + 1), r2 = __shfl(rX, j + 2), r3 = __shfl(rX, j + 3);
      float w0 = __int_as_float(__shfl(rW, j + 0)), w1 = __int_as_float(__shfl(rW, j + 1));
      float w2 = __int_as_float(__shfl(rW, j + 2)), w3 = __int_as_float(__shfl(rW, j + 3));
      doGather(r0, w0);
      doGather(r1, w1);
      doGather(r2, w2);
      doGather(r3, w3);
    }
    for (; j < rem; ++j) {
      int   r0 = __shfl(rX, j);
      float w0 = __int_as_float(__shfl(rW, j));
      doGather(r0, w0);
    }
    // ---- edge MLP via MFMA: 16 edges per group ----
    for (int g = 0; g * 16 < rem; ++g) {
      int idx = g * 16 + mrow;
      bool valid = idx < rem;
      short8 a = {0, 0, 0, 0, 0, 0, 0, 0};
      if (quad < 2) {
        if (valid)
          a = *(const short8*)(const void*)(attr_bf + (((size_t)(base + idx)) << 4) + quad * 8);
      } else if (quad == 2) {
        a[0] = valid ? (short)0x3F80 : (short)0;   // constant-1 slot at k=16 folds b1, zeroes pad rows
      }
      floatx4 zeroc = {0.f, 0.f, 0.f, 0.f};
      floatx4 dacc[8];
      #pragma unroll
      for (int tt = 0; tt < 8; ++tt)
        dacc[tt] = __builtin_amdgcn_mfma_f32_16x16x32_bf16(a, bfr[tt], zeroc, 0, 0, 0);
      #pragma unroll
      for (int tt = 0; tt < 8; ++tt) {
        float s = fmaxf(dacc[tt][0], 0.f) + fmaxf(dacc[tt][1], 0.f) +
                  fmaxf(dacc[tt][2], 0.f) + fmaxf(dacc[tt][3], 0.f);
        s += __shfl_xor(s, 16);
        s += __shfl_xor(s, 32);
        sE[tt] += s;
      }
    }
  }
  unsigned short* rowp = Abuf + (size_t)n * 256;
  ((unsigned*)rowp)[lane] = (unsigned)f2bf(aH0) | ((unsigned)f2bf(aH1) << 16);
  #pragma unroll
  for (int tt = 0; tt < 8; ++tt)
    if ((tt >> 1) == quad) rowp[128 + tt * 16 + mrow] = f2bf(sE[tt]);
}

// ---------------- fused MFMA GEMM (K=256) + bias/deg + LayerNorm + relu ----------------

template <bool LAST>
__global__ __launch_bounds__(256, 4) void k_fused(
    const unsigned short* __restrict__ Abuf,   // [NPAD][256] bf16
    const unsigned short* __restrict__ wtL,    // [2][128][128] bf16 (this layer)
    const int* __restrict__ cnt,
    const float* __restrict__ b2, const float* __restrict__ bias,
    const float* __restrict__ lnw, const float* __restrict__ lnb,
    unsigned short* __restrict__ hOut, float* __restrict__ fOut) {
  __shared__ unsigned short bt[128 * 128];   // XOR-swizzled 16B chunks
  int t = threadIdx.x;
  int w = t >> 6, lane = t & 63;
  int quad = lane >> 4, ln = lane & 15;
  int rowBase = blockIdx.x * 64 + w * 16;

  floatx4 acc[8];
  floatx4 zero = {0.f, 0.f, 0.f, 0.f};
  #pragma unroll
  for (int i = 0; i < 8; ++i) acc[i] = zero;

  float b2n[8], biasn[8], lnwn[8], lnbn[8];
  #pragma unroll
  for (int i = 0; i < 8; ++i) {
    int nc = i * 16 + ln;
    b2n[i] = b2[nc]; biasn[i] = bias[nc]; lnwn[i] = lnw[nc]; lnbn[i] = lnb[nc];
  }

  const unsigned short* Arow = Abuf + (size_t)(rowBase + ln) * 256;

  #pragma unroll
  for (int p = 0; p < 2; ++p) {
    if (p) __syncthreads();
    const unsigned short* src = wtL + p * (D * D);
    #pragma unroll
    for (int j = 0; j < 8; ++j) {
      int E = t * 8 + j * 2048;                  // element index: n*128 + k
      int nn_ = E >> 7, kblk = (E & 127) >> 3;
      int dst = nn_ * 128 + ((kblk ^ (nn_ & 15)) << 3);
      *(ushort8*)&bt[dst] = *(const ushort8*)&src[E];
    }
    __syncthreads();
    #pragma unroll
    for (int k0 = 0; k0 < 128; k0 += 32) {
      short8 a = *(const short8*)(const void*)(Arow + p * 128 + k0 + quad * 8);
      int cblk = (k0 >> 3) + quad;
      #pragma unroll
      for (int tt = 0; tt < 8; ++tt) {
        int src_off = (tt * 16 + ln) * 128 + ((cblk ^ ln) << 3);
        short8 b = *(const short8*)(const void*)&bt[src_off];
        acc[tt] = __builtin_amdgcn_mfma_f32_16x16x32_bf16(a, b, acc[tt], 0, 0, 0);
      }
    }
  }

  // epilogue: D[m=quad*4+r][n=tt*16+ln]
  float degf[4];
  #pragma unroll
  for (int r = 0; r < 4; ++r) {
    int m = rowBase + quad * 4 + r;
    degf[r] = (m < NN) ? (float)cnt[m] : 0.f;
  }
  float v[8][4];
  float s[4] = {0, 0, 0, 0}, sq[4] = {0, 0, 0, 0};
  #pragma unroll
  for (int tt = 0; tt < 8; ++tt) {
    #pragma unroll
    for (int r = 0; r < 4; ++r) {
      float x = acc[tt][r] + degf[r] * b2n[tt] + biasn[tt];
      v[tt][r] = x;
      s[r] += x;
      sq[r] += x * x;
    }
  }
  #pragma unroll
  for (int r = 0; r < 4; ++r) {
    #pragma unroll
    for (int m_ = 8; m_ >= 1; m_ >>= 1) {
      s[r] += __shfl_xor(s[r], m_);
      sq[r] += __shfl_xor(sq[r], m_);
    }
  }
  #pragma unroll
  for (int r = 0; r < 4; ++r) {
    int m = rowBase + quad * 4 + r;
    float mu = s[r] * (1.f / D);
    float var = sq[r] * (1.f / D) - mu * mu;
    float rs = rsqrtf(var + LN_EPS);
    if (m < NN) {
      #pragma unroll
      for (int tt = 0; tt < 8; ++tt) {
        float y = fmaxf((v[tt][r] - mu) * rs * lnwn[tt] + lnbn[tt], 0.f);
        int nc = tt * 16 + ln;
        if (LAST) fOut[(size_t)m * D + nc] = y;
        else      hOut[(size_t)m * D + nc] = f2bf(y);
      }
    }
  }
}

// ---------------- launch ----------------

static inline size_t align256(size_t x) { return (x + 255) & ~(size_t)255; }

extern "C" void kernel_launch(void* const* d_in, const int* in_sizes, int n_in,
                              void* d_out, int out_size, void* d_ws, size_t ws_size,
                              hipStream_t stream) {
  const float* x         = (const float*)d_in[0];
  const float* edge_attr = (const float*)d_in[1];
  const float* lin_w     = (const float*)d_in[2];
  const float* edge_w1   = (const float*)d_in[3];
  const float* edge_b1   = (const float*)d_in[4];
  const float* edge_w2   = (const float*)d_in[5];
  const float* edge_b2   = (const float*)d_in[6];
  const float* bias      = (const float*)d_in[7];
  const float* ln_w      = (const float*)d_in[8];
  const float* ln_b      = (const float*)d_in[9];
  const int*   edge_idx  = (const int*)d_in[10];
  const int* row = edge_idx;
  const int* col = edge_idx + NE;
  float* out = (float*)d_out;

  char* wsp = (char*)d_ws;
  size_t off = 0;
  int* cnt       = (int*)(wsp + off); off = align256(off + sizeof(int) * NN);
  int* cursor    = (int*)(wsp + off); off = align256(off + sizeof(int) * NN);
  int* col_ptr   = (int*)(wsp + off); off = align256(off + sizeof(int) * (NN + 1));
  float* dis     = (float*)(wsp + off); off = align256(off + sizeof(float) * NN);
  int* chunk_sum = (int*)(wsp + off); off = align256(off + sizeof(int) * 64);
  int* chunk_off = (int*)(wsp + off); off = align256(off + sizeof(int) * 64);
  int2* csr_rw   = (int2*)(wsp + off); off = align256(off + sizeof(int2) * NE);
  int* csr_eid   = (int*)(wsp + off); off = align256(off + sizeof(int) * NE);
  unsigned short* attr_bf = (unsigned short*)(wsp + off); off = align256(off + sizeof(short) * (size_t)NE * DE);
  unsigned short* wt  = (unsigned short*)(wsp + off); off = align256(off + sizeof(short) * NL * 2 * D * D);
  unsigned short* w1t = (unsigned short*)(wsp + off); off = align256(off + sizeof(short) * NL * D * 32);
  unsigned short* hA = (unsigned short*)(wsp + off); off = align256(off + sizeof(short) * (size_t)NPAD * D);
  unsigned short* hB = (unsigned short*)(wsp + off); off = align256(off + sizeof(short) * (size_t)NPAD * D);
  unsigned short* Abuf = (unsigned short*)(wsp + off); off = align256(off + sizeof(short) * (size_t)NPAD * 256);

  hipMemsetAsync(cnt, 0, sizeof(int) * NN, stream);

  k_hist<<<(NE + 255) / 256, 256, 0, stream>>>(col, cnt);
  k_chunk_sum<<<NB_SCAN, 1024, 0, stream>>>(cnt, chunk_sum);
  k_chunk_scan<<<1, 64, 0, stream>>>(chunk_sum, chunk_off, col_ptr);
  k_scan_apply<<<NB_SCAN, 1024, 0, stream>>>(cnt, chunk_off, col_ptr, cursor, dis);
  k_fill<<<(NE + 255) / 256, 256, 0, stream>>>(row, col, dis, cursor, csr_rw, csr_eid);
  k_cvt_attr<<<(NE + 255) / 256, 256, 0, stream>>>(edge_attr, csr_eid, attr_bf);
  k_prep_w<<<(NL * 2 * D * D + 255) / 256, 256, 0, stream>>>(lin_w, edge_w2, wt);
  k_prep_w1<<<(NL * D * 32 + 255) / 256, 256, 0, stream>>>(edge_w1, edge_b1, w1t);
  k_cvt_x<<<(NN * D / 4 + 255) / 256, 256, 0, stream>>>(x, hA);

  const int fused_blocks = NPAD / 64;
  unsigned short* hcur = hA;
  unsigned short* hnxt = hB;
  for (int l = 0; l < NL; ++l) {
    k_agg<<<(NN + 3) / 4, 256, 0, stream>>>(
        hcur, attr_bf, w1t + (size_t)l * D * 32, col_ptr, csr_rw, Abuf);
    const unsigned short* wtL = wt + (size_t)l * 2 * D * D;
    const float* b2L = edge_b2 + (size_t)l * D;
    const float* biasL = bias + (size_t)l * D;
    const float* lnwL = ln_w + (size_t)l * D;
    const float* lnbL = ln_b + (size_t)l * D;
    if (l == NL - 1) {
      k_fused<true><<<fused_blocks, 256, 0, stream>>>(Abuf, wtL, cnt, b2L, biasL, lnwL, lnbL,
                                                      (unsigned short*)nullptr, out);
    } else {
      k_fused<false><<<fused_blocks, 256, 0, stream>>>(Abuf, wtL, cnt, b2L, biasL, lnwL, lnbL,
                                                       hnxt, (float*)nullptr);
    }
    unsigned short* tmp = hcur; hcur = hnxt; hnxt = tmp;
  }
}

// Round 4
// 476.646 us; speedup vs baseline: 1.8889x; 1.0470x over previous
//
#include <hip/hip_runtime.h>
#include <math.h>

#define NN 50000
#define NPAD 50048           // 782 * 64
#define NE 800000
#define D 128
#define DE 16
#define NL 3
#define LN_EPS 1e-5f
#define NB_SCAN 49           // ceil(50000/1024)

typedef __attribute__((ext_vector_type(8))) short short8;
typedef __attribute__((ext_vector_type(8))) unsigned short ushort8;
typedef __attribute__((ext_vector_type(4))) float floatx4;

__device__ __forceinline__ unsigned short f2bf(float f) {
  unsigned u = __float_as_uint(f);
  u = (u + 0x7fffu + ((u >> 16) & 1u)) >> 16;
  return (unsigned short)u;
}
__device__ __forceinline__ float bfl(unsigned v) { return __uint_as_float(v << 16); }
__device__ __forceinline__ float bfh(unsigned v) { return __uint_as_float(v & 0xffff0000u); }

// ---------------- preprocessing ----------------

__global__ void k_hist(const int* __restrict__ col, int* __restrict__ cnt) {
  int e = blockIdx.x * blockDim.x + threadIdx.x;
  if (e < NE) atomicAdd(&cnt[col[e]], 1);
}

__global__ __launch_bounds__(1024) void k_chunk_sum(const int* __restrict__ cnt,
                                                    int* __restrict__ chunk_sum) {
  int i = blockIdx.x * 1024 + threadIdx.x;
  int v = (i < NN) ? cnt[i] : 0;
  #pragma unroll
  for (int off = 32; off; off >>= 1) v += __shfl_down(v, off);
  __shared__ int ws_[16];
  int lane = threadIdx.x & 63, w = threadIdx.x >> 6;
  if (lane == 0) ws_[w] = v;
  __syncthreads();
  if (threadIdx.x < 16) {
    int s = ws_[threadIdx.x];
    #pragma unroll
    for (int off = 8; off; off >>= 1) s += __shfl_down(s, off);
    if (threadIdx.x == 0) chunk_sum[blockIdx.x] = s;
  }
}

__global__ __launch_bounds__(64) void k_chunk_scan(const int* __restrict__ chunk_sum,
                                                   int* __restrict__ chunk_off,
                                                   int* __restrict__ col_ptr) {
  int t = threadIdx.x;
  int v = (t < NB_SCAN) ? chunk_sum[t] : 0;
  int incl = v;
  #pragma unroll
  for (int off = 1; off < 64; off <<= 1) {
    int u = __shfl_up(incl, off);
    if (t >= off) incl += u;
  }
  if (t < NB_SCAN) chunk_off[t] = incl - v;
  if (t == 63) col_ptr[NN] = incl;   // total == NE
}

__global__ __launch_bounds__(1024) void k_scan_apply(const int* __restrict__ cnt,
                                                     const int* __restrict__ chunk_off,
                                                     int* __restrict__ col_ptr,
                                                     int* __restrict__ cursor,
                                                     float* __restrict__ dis) {
  __shared__ int buf[1024];
  int t = threadIdx.x;
  int i = blockIdx.x * 1024 + t;
  int v = (i < NN) ? cnt[i] : 0;
  buf[t] = v;
  __syncthreads();
  int acc = v;
  for (int off = 1; off < 1024; off <<= 1) {
    int add = (t >= off) ? buf[t - off] : 0;
    __syncthreads();
    acc += add;
    buf[t] = acc;
    __syncthreads();
  }
  if (i < NN) {
    int cp = chunk_off[blockIdx.x] + acc - v;
    col_ptr[i] = cp;
    cursor[i] = cp;
    dis[i] = (v > 0) ? rsqrtf((float)v) : 0.0f;
  }
}

// fill CSR (row, weight) and permute+convert edge_attr to CSR order bf16 in one pass
__global__ void k_fill(const int* __restrict__ row, const int* __restrict__ col,
                       const float* __restrict__ dis, int* __restrict__ cursor,
                       const float* __restrict__ edge_attr,
                       int2* __restrict__ csr_rw, unsigned short* __restrict__ attr_bf) {
  int e = blockIdx.x * blockDim.x + threadIdx.x;
  if (e >= NE) return;
  int c = col[e], r = row[e];
  float w = dis[r] * dis[c];
  int p = atomicAdd(&cursor[c], 1);
  csr_rw[p] = make_int2(r, __float_as_int(w));
  const float4* src = (const float4*)(edge_attr + ((size_t)e << 4));
  float4 f0 = src[0], f1 = src[1], f2 = src[2], f3 = src[3];
  ushort8 o0, o1;
  o0[0] = f2bf(f0.x); o0[1] = f2bf(f0.y); o0[2] = f2bf(f0.z); o0[3] = f2bf(f0.w);
  o0[4] = f2bf(f1.x); o0[5] = f2bf(f1.y); o0[6] = f2bf(f1.z); o0[7] = f2bf(f1.w);
  o1[0] = f2bf(f2.x); o1[1] = f2bf(f2.y); o1[2] = f2bf(f2.z); o1[3] = f2bf(f2.w);
  o1[4] = f2bf(f3.x); o1[5] = f2bf(f3.y); o1[6] = f2bf(f3.z); o1[7] = f2bf(f3.w);
  ushort8* dst = (ushort8*)(attr_bf + ((size_t)p << 4));
  dst[0] = o0;
  dst[1] = o1;
}

// convert+transpose weights: wt[(l*2+s)][n][k] = W_s[l][k][n] in bf16
__global__ void k_prep_w(const float* __restrict__ lin_w, const float* __restrict__ edge_w2,
                         unsigned short* __restrict__ wt) {
  int idx = blockIdx.x * blockDim.x + threadIdx.x;
  if (idx >= NL * 2 * D * D) return;
  int ls = idx / (D * D);
  int rem = idx - ls * (D * D);
  int n = rem >> 7, k = rem & 127;
  int l = ls >> 1, s = ls & 1;
  const float* W = (s == 0) ? (lin_w + (size_t)l * D * D) : (edge_w2 + (size_t)l * D * D);
  wt[idx] = f2bf(W[k * D + n]);
}

// W1^T fragments: w1t[l][n][k], k in [0,32): k<16 -> W1[k][n]; k==16 -> b1[n]; else 0
__global__ void k_prep_w1(const float* __restrict__ edge_w1, const float* __restrict__ edge_b1,
                          unsigned short* __restrict__ w1t) {
  int idx = blockIdx.x * blockDim.x + threadIdx.x;
  if (idx >= NL * D * 32) return;
  int l = idx / (D * 32);
  int rem = idx - l * (D * 32);
  int nf = rem >> 5, k = rem & 31;
  float v = 0.f;
  if (k < DE) v = edge_w1[(size_t)l * DE * D + k * D + nf];
  else if (k == DE) v = edge_b1[(size_t)l * D + nf];
  w1t[idx] = f2bf(v);
}

__global__ void k_cvt_x(const float* __restrict__ x, unsigned short* __restrict__ h) {
  int i = blockIdx.x * blockDim.x + threadIdx.x;
  if (i >= NN * D / 4) return;
  float4 v = ((const float4*)x)[i];
  ushort4 o;
  o.x = f2bf(v.x); o.y = f2bf(v.y); o.z = f2bf(v.z); o.w = f2bf(v.w);
  ((ushort4*)h)[i] = o;
}

// ---------------- acc_e for ALL layers in one pass (wave per node) ----------------
// Ebuf[l][n][:] = sum_e relu(attr_e @ W1_l + b1_l)   via MFMA per 16-edge group

__global__ __launch_bounds__(256, 2) void k_agg_e(
    const unsigned short* __restrict__ attr_bf,
    const unsigned short* __restrict__ w1t,     // [NL][128][32]
    const int* __restrict__ col_ptr,
    unsigned short* __restrict__ Ebuf) {        // [NL][NPAD][128]
  int t = threadIdx.x;
  int lane = t & 63;
  int quad = lane >> 4, mrow = lane & 15;
  int n = blockIdx.x * 4 + (t >> 6);
  if (n >= NN) return;

  short8 bfr[NL][8];
  #pragma unroll
  for (int l = 0; l < NL; ++l)
    #pragma unroll
    for (int tt = 0; tt < 8; ++tt)
      bfr[l][tt] = *(const short8*)(const void*)(w1t + l * D * 32 + (tt * 16 + mrow) * 32 + quad * 8);

  int p0 = col_ptr[n], p1 = col_ptr[n + 1];
  float sE[NL][8];
  #pragma unroll
  for (int l = 0; l < NL; ++l)
    #pragma unroll
    for (int tt = 0; tt < 8; ++tt) sE[l][tt] = 0.f;

  for (int base = p0; base < p1; base += 16) {
    bool valid = base + mrow < p1;
    short8 a = {0, 0, 0, 0, 0, 0, 0, 0};
    if (quad < 2) {
      if (valid)
        a = *(const short8*)(const void*)(attr_bf + (((size_t)(base + mrow)) << 4) + quad * 8);
    } else if (quad == 2) {
      a[0] = valid ? (short)0x3F80 : (short)0;   // k=16 constant-1 slot folds b1, zeroes pad rows
    }
    floatx4 zeroc = {0.f, 0.f, 0.f, 0.f};
    #pragma unroll
    for (int l = 0; l < NL; ++l) {
      #pragma unroll
      for (int tt = 0; tt < 8; ++tt) {
        floatx4 dacc = __builtin_amdgcn_mfma_f32_16x16x32_bf16(a, bfr[l][tt], zeroc, 0, 0, 0);
        float s = fmaxf(dacc[0], 0.f) + fmaxf(dacc[1], 0.f) +
                  fmaxf(dacc[2], 0.f) + fmaxf(dacc[3], 0.f);
        s += __shfl_xor(s, 16);
        s += __shfl_xor(s, 32);
        sE[l][tt] += s;
      }
    }
  }
  #pragma unroll
  for (int l = 0; l < NL; ++l) {
    unsigned short* rowp = Ebuf + ((size_t)l * NPAD + n) * 128;
    #pragma unroll
    for (int tt = 0; tt < 8; ++tt)
      if ((tt >> 1) == quad) rowp[tt * 16 + mrow] = f2bf(sE[l][tt]);
  }
}

// ---------------- h-gather (wave per node, 4 edges per load) ----------------
// Hbuf[n][:] = sum_e w_e * h[row_e]

__global__ __launch_bounds__(256, 8) void k_agg_h(
    const unsigned short* __restrict__ hIn,
    const int* __restrict__ col_ptr, const int2* __restrict__ csr_rw,
    unsigned short* __restrict__ Hbuf) {
  int t = threadIdx.x;
  int lane = t & 63;
  int sub = lane >> 4, fl = lane & 15;   // lane covers features fl*8..fl*8+7 of edge slot sub
  int n = blockIdx.x * 4 + (t >> 6);
  if (n >= NN) return;
  int p0 = col_ptr[n], p1 = col_ptr[n + 1];
  float aH[8];
  #pragma unroll
  for (int k = 0; k < 8; ++k) aH[k] = 0.f;

  for (int base = p0; base < p1; base += 64) {
    int rem = p1 - base;
    if (rem > 64) rem = 64;
    int rX = 0, rW = 0;
    if (lane < rem) {
      int2 q = csr_rw[base + lane];
      rX = q.x; rW = q.y;
    }
    #pragma unroll 2
    for (int j = 0; j < rem; j += 4) {
      int idx = j + sub;
      int ri = __shfl(rX, idx);
      int wb = __shfl(rW, idx);
      bool v = idx < rem;
      float wi = v ? __int_as_float(wb) : 0.f;
      ri = v ? ri : 0;
      uint4 hv = *(const uint4*)(hIn + (((size_t)ri) << 7) + (fl << 3));
      aH[0] = fmaf(wi, bfl(hv.x), aH[0]);
      aH[1] = fmaf(wi, bfh(hv.x), aH[1]);
      aH[2] = fmaf(wi, bfl(hv.y), aH[2]);
      aH[3] = fmaf(wi, bfh(hv.y), aH[3]);
      aH[4] = fmaf(wi, bfl(hv.z), aH[4]);
      aH[5] = fmaf(wi, bfh(hv.z), aH[5]);
      aH[6] = fmaf(wi, bfl(hv.w), aH[6]);
      aH[7] = fmaf(wi, bfh(hv.w), aH[7]);
    }
  }
  #pragma unroll
  for (int k = 0; k < 8; ++k) {
    aH[k] += __shfl_xor(aH[k], 16);
    aH[k] += __shfl_xor(aH[k], 32);
  }
  if (sub == 0) {
    uint4 o;
    o.x = (unsigned)f2bf(aH[0]) | ((unsigned)f2bf(aH[1]) << 16);
    o.y = (unsigned)f2bf(aH[2]) | ((unsigned)f2bf(aH[3]) << 16);
    o.z = (unsigned)f2bf(aH[4]) | ((unsigned)f2bf(aH[5]) << 16);
    o.w = (unsigned)f2bf(aH[6]) | ((unsigned)f2bf(aH[7]) << 16);
    *(uint4*)(Hbuf + ((size_t)n << 7) + (fl << 3)) = o;
  }
}

// ---------------- fused MFMA GEMM (K=256) + bias/deg + LayerNorm + relu ----------------
// A = [Hbuf | Ebuf_l]  (two 128-wide slabs)

template <bool LAST>
__global__ __launch_bounds__(256, 4) void k_fused(
    const unsigned short* __restrict__ Hbuf,   // [NPAD][128] bf16
    const unsigned short* __restrict__ EbufL,  // [NPAD][128] bf16
    const unsigned short* __restrict__ wtL,    // [2][128][128] bf16 (this layer)
    const int* __restrict__ cnt,
    const float* __restrict__ b2, const float* __restrict__ bias,
    const float* __restrict__ lnw, const float* __restrict__ lnb,
    unsigned short* __restrict__ hOut, float* __restrict__ fOut) {
  __shared__ unsigned short bt[128 * 128];   // XOR-swizzled 16B chunks
  int t = threadIdx.x;
  int w = t >> 6, lane = t & 63;
  int quad = lane >> 4, ln = lane & 15;
  int rowBase = blockIdx.x * 64 + w * 16;

  floatx4 acc[8];
  floatx4 zero = {0.f, 0.f, 0.f, 0.f};
  #pragma unroll
  for (int i = 0; i < 8; ++i) acc[i] = zero;

  float b2n[8], biasn[8], lnwn[8], lnbn[8];
  #pragma unroll
  for (int i = 0; i < 8; ++i) {
    int nc = i * 16 + ln;
    b2n[i] = b2[nc]; biasn[i] = bias[nc]; lnwn[i] = lnw[nc]; lnbn[i] = lnb[nc];
  }

  #pragma unroll
  for (int p = 0; p < 2; ++p) {
    if (p) __syncthreads();
    const unsigned short* src = wtL + p * (D * D);
    #pragma unroll
    for (int j = 0; j < 8; ++j) {
      int E = t * 8 + j * 2048;                  // element index: n*128 + k
      int nn_ = E >> 7, kblk = (E & 127) >> 3;
      int dst = nn_ * 128 + ((kblk ^ (nn_ & 15)) << 3);
      *(ushort8*)&bt[dst] = *(const ushort8*)&src[E];
    }
    __syncthreads();
    const unsigned short* Arow =
        (p == 0 ? Hbuf : EbufL) + (size_t)(rowBase + ln) * 128;
    #pragma unroll
    for (int k0 = 0; k0 < 128; k0 += 32) {
      short8 a = *(const short8*)(const void*)(Arow + k0 + quad * 8);
      int cblk = (k0 >> 3) + quad;
      #pragma unroll
      for (int tt = 0; tt < 8; ++tt) {
        int src_off = (tt * 16 + ln) * 128 + ((cblk ^ ln) << 3);
        short8 b = *(const short8*)(const void*)&bt[src_off];
        acc[tt] = __builtin_amdgcn_mfma_f32_16x16x32_bf16(a, b, acc[tt], 0, 0, 0);
      }
    }
  }

  // epilogue: D[m=quad*4+r][n=tt*16+ln]
  float degf[4];
  #pragma unroll
  for (int r = 0; r < 4; ++r) {
    int m = rowBase + quad * 4 + r;
    degf[r] = (m < NN) ? (float)cnt[m] : 0.f;
  }
  float v[8][4];
  float s[4] = {0, 0, 0, 0}, sq[4] = {0, 0, 0, 0};
  #pragma unroll
  for (int tt = 0; tt < 8; ++tt) {
    #pragma unroll
    for (int r = 0; r < 4; ++r) {
      float x = acc[tt][r] + degf[r] * b2n[tt] + biasn[tt];
      v[tt][r] = x;
      s[r] += x;
      sq[r] += x * x;
    }
  }
  #pragma unroll
  for (int r = 0; r < 4; ++r) {
    #pragma unroll
    for (int m_ = 8; m_ >= 1; m_ >>= 1) {
      s[r] += __shfl_xor(s[r], m_);
      sq[r] += __shfl_xor(sq[r], m_);
    }
  }
  #pragma unroll
  for (int r = 0; r < 4; ++r) {
    int m = rowBase + quad * 4 + r;
    float mu = s[r] * (1.f / D);
    float var = sq[r] * (1.f / D) - mu * mu;
    float rs = rsqrtf(var + LN_EPS);
    if (m < NN) {
      #pragma unroll
      for (int tt = 0; tt < 8; ++tt) {
        float y = fmaxf((v[tt][r] - mu) * rs * lnwn[tt] + lnbn[tt], 0.f);
        int nc = tt * 16 + ln;
        if (LAST) fOut[(size_t)m * D + nc] = y;
        else      hOut[(size_t)m * D + nc] = f2bf(y);
      }
    }
  }
}

// ---------------- launch ----------------

static inline size_t align256(size_t x) { return (x + 255) & ~(size_t)255; }

extern "C" void kernel_launch(void* const* d_in, const int* in_sizes, int n_in,
                              void* d_out, int out_size, void* d_ws, size_t ws_size,
                              hipStream_t stream) {
  const float* x         = (const float*)d_in[0];
  const float* edge_attr = (const float*)d_in[1];
  const float* lin_w     = (const float*)d_in[2];
  const float* edge_w1   = (const float*)d_in[3];
  const float* edge_b1   = (const float*)d_in[4];
  const float* edge_w2   = (const float*)d_in[5];
  const float* edge_b2   = (const float*)d_in[6];
  const float* bias      = (const float*)d_in[7];
  const float* ln_w      = (const float*)d_in[8];
  const float* ln_b      = (const float*)d_in[9];
  const int*   edge_idx  = (const int*)d_in[10];
  const int* row = edge_idx;
  const int* col = edge_idx + NE;
  float* out = (float*)d_out;

  char* wsp = (char*)d_ws;
  size_t off = 0;
  int* cnt       = (int*)(wsp + off); off = align256(off + sizeof(int) * NN);
  int* cursor    = (int*)(wsp + off); off = align256(off + sizeof(int) * NN);
  int* col_ptr   = (int*)(wsp + off); off = align256(off + sizeof(int) * (NN + 1));
  float* dis     = (float*)(wsp + off); off = align256(off + sizeof(float) * NN);
  int* chunk_sum = (int*)(wsp + off); off = align256(off + sizeof(int) * 64);
  int* chunk_off = (int*)(wsp + off); off = align256(off + sizeof(int) * 64);
  int2* csr_rw   = (int2*)(wsp + off); off = align256(off + sizeof(int2) * NE);
  unsigned short* attr_bf = (unsigned short*)(wsp + off); off = align256(off + sizeof(short) * (size_t)NE * DE);
  unsigned short* wt  = (unsigned short*)(wsp + off); off = align256(off + sizeof(short) * NL * 2 * D * D);
  unsigned short* w1t = (unsigned short*)(wsp + off); off = align256(off + sizeof(short) * NL * D * 32);
  unsigned short* hA = (unsigned short*)(wsp + off); off = align256(off + sizeof(short) * (size_t)NPAD * D);
  unsigned short* hB = (unsigned short*)(wsp + off); off = align256(off + sizeof(short) * (size_t)NPAD * D);
  unsigned short* Hbuf = (unsigned short*)(wsp + off); off = align256(off + sizeof(short) * (size_t)NPAD * D);
  unsigned short* Ebuf = (unsigned short*)(wsp + off); off = align256(off + sizeof(short) * (size_t)NL * NPAD * D);

  hipMemsetAsync(cnt, 0, sizeof(int) * NN, stream);

  k_hist<<<(NE + 255) / 256, 256, 0, stream>>>(col, cnt);
  k_chunk_sum<<<NB_SCAN, 1024, 0, stream>>>(cnt, chunk_sum);
  k_chunk_scan<<<1, 64, 0, stream>>>(chunk_sum, chunk_off, col_ptr);
  k_scan_apply<<<NB_SCAN, 1024, 0, stream>>>(cnt, chunk_off, col_ptr, cursor, dis);
  k_fill<<<(NE + 255) / 256, 256, 0, stream>>>(row, col, dis, cursor, edge_attr, csr_rw, attr_bf);
  k_prep_w<<<(NL * 2 * D * D + 255) / 256, 256, 0, stream>>>(lin_w, edge_w2, wt);
  k_prep_w1<<<(NL * D * 32 + 255) / 256, 256, 0, stream>>>(edge_w1, edge_b1, w1t);
  k_cvt_x<<<(NN * D / 4 + 255) / 256, 256, 0, stream>>>(x, hA);

  k_agg_e<<<(NN + 3) / 4, 256, 0, stream>>>(attr_bf, w1t, col_ptr, Ebuf);

  const int fused_blocks = NPAD / 64;
  unsigned short* hcur = hA;
  unsigned short* hnxt = hB;
  for (int l = 0; l < NL; ++l) {
    k_agg_h<<<(NN + 3) / 4, 256, 0, stream>>>(hcur, col_ptr, csr_rw, Hbuf);
    const unsigned short* wtL = wt + (size_t)l * 2 * D * D;
    const unsigned short* EbufL = Ebuf + (size_t)l * NPAD * D;
    const float* b2L = edge_b2 + (size_t)l * D;
    const float* biasL = bias + (size_t)l * D;
    const float* lnwL = ln_w + (size_t)l * D;
    const float* lnbL = ln_b + (size_t)l * D;
    if (l == NL - 1) {
      k_fused<true><<<fused_blocks, 256, 0, stream>>>(Hbuf, EbufL, wtL, cnt, b2L, biasL, lnwL, lnbL,
                                                      (unsigned short*)nullptr, out);
    } else {
      k_fused<false><<<fused_blocks, 256, 0, stream>>>(Hbuf, EbufL, wtL, cnt, b2L, biasL, lnwL, lnbL,
                                                       hnxt, (float*)nullptr);
    }
    unsigned short* tmp = hcur; hcur = hnxt; hnxt = tmp;
  }
}